// Round 3
// baseline (575.686 us; speedup 1.0000x reference)
//
#include <hip/hip_runtime.h>
#include <hip/hip_cooperative_groups.h>
#include <math.h>

namespace cg = cooperative_groups;

#define B_      4
#define IN_DIM  512
#define HID     1024
#define SEQ     4096
#define MID_DIM 12352          // 2*64*64 + 65*64
#define MLP_OUT 24897          // RL*MID_DIM + OUT_DIM
#define INV2PI  0.15915494309189535f

// transposed/pre-scaled weight layout, per b (stride MLPT_STRIDE):
//  layer l in {0,1} at l*12416: wsc[i][o] | wof[i][o] | bsv[i][o] | bc[o] | pad
//  out layer at 24832: wsO/2pi | woO/2pi | bsO | bcO | pad to 256
#define MLPT_STRIDE 25088

// ---- workspace layout (float offsets) ----
#define OFF_P0    0            // 8*4*1024  = 32768
#define OFF_P1    32768        // 16*4*1024 = 65536
#define OFF_P2    98304        // 16*4*1024 = 65536
#define OFF_P3    163840       // 4*4*24897 = 398352
#define OFF_MLPT  562192       // 4*25088   = 100352

__device__ __forceinline__ float gelu_exact(float v) {
    return 0.5f * v * (1.0f + erff(v * 0.70710678118654752f));
}

__device__ __forceinline__ float hw_sin_rev(float r) {
    r = r - __builtin_rintf(r);
    return __builtin_amdgcn_sinf(r);
}

__global__ void __launch_bounds__(256, 2) k_mega(
    const float* __restrict__ x,  const float* __restrict__ w0, const float* __restrict__ b0,
    const float* __restrict__ w1, const float* __restrict__ b1, const float* __restrict__ g1,
    const float* __restrict__ bl1,
    const float* __restrict__ w2, const float* __restrict__ b2, const float* __restrict__ g2,
    const float* __restrict__ bl2,
    const float* __restrict__ w3, const float* __restrict__ b3,
    const float* __restrict__ lcw, const float* __restrict__ lcb,
    const float* __restrict__ bypw, const float* __restrict__ bypb,
    float* __restrict__ out, float* __restrict__ ws)
{
    cg::grid_group grid = cg::this_grid();
    const int tid = threadIdx.x;
    const int nblk = gridDim.x;

    float* p0   = ws + OFF_P0;
    float* p1   = ws + OFF_P1;
    float* p2   = ws + OFF_P2;
    float* p3   = ws + OFF_P3;
    float* mlpT = ws + OFF_MLPT;

    __shared__ __align__(16) float s_w[12416];   // ripple weights / vbuf for LN phases
    __shared__ __align__(16) float s_x[2304];    // ripple x[i][t] stride 36
    __shared__ __align__(16) float s_wo[256];
    __shared__ float s_red[64];
    __shared__ float s_hs[256];

    // ================= phase 0: x(4x512) @ w0 -> p0 (8 K-partials), 128 tasks ==========
    for (int task = blockIdx.x; task < 128; task += nblk) {
        const int cch = task >> 3, kc = task & 7;
        {
            const int b = tid >> 6, k = tid & 63;
            s_hs[tid] = x[b * IN_DIM + kc * 64 + k];
        }
        __syncthreads();
        const int b = tid >> 6, cl = tid & 63;
        const int c = cch * 64 + cl;
        const float* wp = w0 + (size_t)(kc * 64) * HID + c;
        const float* xp = s_hs + b * 64;
        float acc = 0.f;
        #pragma unroll 8
        for (int k = 0; k < 64; ++k) acc = fmaf(xp[k], wp[(size_t)k * HID], acc);
        p0[(kc * 4 + b) * HID + c] = acc;
        __syncthreads();
    }
    grid.sync();

    // ================= phase 1: h0=gelu(sum p0 + b0); h0 @ w1 -> p1 (16 partials), 256 tasks
    for (int task = blockIdx.x; task < 256; task += nblk) {
        const int cch = task >> 4, kc = task & 15;
        {
            const int b = tid >> 6, k = tid & 63;
            const int kg = kc * 64 + k;
            float v = b0[kg];
            #pragma unroll
            for (int j = 0; j < 8; ++j) v += p0[(j * 4 + b) * HID + kg];
            s_hs[tid] = gelu_exact(v);
        }
        __syncthreads();
        const int b = tid >> 6, cl = tid & 63;
        const int c = cch * 64 + cl;
        const float* wp = w1 + (size_t)(kc * 64) * HID + c;
        const float* hp = s_hs + b * 64;
        float acc = 0.f;
        #pragma unroll 8
        for (int k = 0; k < 64; ++k) acc = fmaf(hp[k], wp[(size_t)k * HID], acc);
        p1[(kc * 4 + b) * HID + c] = acc;
        __syncthreads();
    }
    grid.sync();

    // ================= phase 2: h1=gelu(LN(sum p1 + b1)); h1 @ w2 -> p2 (16 partials), 256 tasks
    for (int task = blockIdx.x; task < 256; task += nblk) {
        const int cch = task >> 4, kc = task & 15;
        float* vbuf = s_w;   // 4096 floats: [b][c]
        for (int e = tid; e < 4096; e += 256) {
            const int b = e >> 10, c = e & 1023;
            float v = b1[c];
            #pragma unroll
            for (int j = 0; j < 16; ++j) v += p1[(j * 4 + b) * HID + c];
            vbuf[e] = v;
        }
        __syncthreads();
        {   // per-b stats: wave w handles b=w
            const int b = tid >> 6, lane = tid & 63;
            float s1 = 0.f, s2 = 0.f;
            #pragma unroll
            for (int j = 0; j < 16; ++j) {
                const float v = vbuf[b * 1024 + lane + 64 * j];
                s1 += v; s2 += v * v;
            }
            #pragma unroll
            for (int m = 1; m < 64; m <<= 1) {
                s1 += __shfl_xor(s1, m, 64);
                s2 += __shfl_xor(s2, m, 64);
            }
            if (lane == 0) {
                const float mu = s1 * (1.0f / HID);
                s_red[b] = mu;
                s_red[4 + b] = rsqrtf(s2 * (1.0f / HID) - mu * mu + 1e-5f);
            }
        }
        __syncthreads();
        {
            const int b = tid >> 6, kl = tid & 63;
            const int c = kc * 64 + kl;
            const float v = vbuf[b * 1024 + c];
            s_hs[tid] = gelu_exact((v - s_red[b]) * s_red[4 + b] * g1[c] + bl1[c]);
        }
        __syncthreads();
        const int b = tid >> 6, cl = tid & 63;
        const int c = cch * 64 + cl;
        const float* wp = w2 + (size_t)(kc * 64) * HID + c;
        const float* hp = s_hs + b * 64;
        float acc = 0.f;
        #pragma unroll 8
        for (int k = 0; k < 64; ++k) acc = fmaf(hp[k], wp[(size_t)k * HID], acc);
        p2[(kc * 4 + b) * HID + c] = acc;
        __syncthreads();
    }
    grid.sync();

    // ================= phase 3: h2=gelu(LN(sum p2 + b2)); h2 @ w3 -> p3 (4 partials), 392 tasks
    for (int task = blockIdx.x; task < 392; task += nblk) {
        const int cch = task >> 2, kc = task & 3;    // cch 0..97, kc 0..3 (K=256)
        float* vbuf = s_w;
        for (int e = tid; e < 4096; e += 256) {
            const int b = e >> 10, c = e & 1023;
            float v = b2[c];
            #pragma unroll
            for (int j = 0; j < 16; ++j) v += p2[(j * 4 + b) * HID + c];
            vbuf[e] = v;
        }
        __syncthreads();
        {
            const int b = tid >> 6, lane = tid & 63;
            float s1 = 0.f, s2 = 0.f;
            #pragma unroll
            for (int j = 0; j < 16; ++j) {
                const float v = vbuf[b * 1024 + lane + 64 * j];
                s1 += v; s2 += v * v;
            }
            #pragma unroll
            for (int m = 1; m < 64; m <<= 1) {
                s1 += __shfl_xor(s1, m, 64);
                s2 += __shfl_xor(s2, m, 64);
            }
            if (lane == 0) {
                const float mu = s1 * (1.0f / HID);
                s_red[b] = mu;
                s_red[4 + b] = rsqrtf(s2 * (1.0f / HID) - mu * mu + 1e-5f);
            }
        }
        __syncthreads();
        for (int e = tid; e < 4096; e += 256) {    // gelu(LN) in place
            const int b = e >> 10, c = e & 1023;
            vbuf[e] = gelu_exact((vbuf[e] - s_red[b]) * s_red[4 + b] * g2[c] + bl2[c]);
        }
        __syncthreads();
        const int c = cch * 256 + tid;
        if (c < MLP_OUT) {
            const float* wp = w3 + (size_t)(kc * 256) * MLP_OUT + c;
            const float* h0p = vbuf + kc * 256;
            float a0 = 0.f, a1 = 0.f, a2 = 0.f, a3 = 0.f;
            #pragma unroll 16
            for (int k = 0; k < 256; ++k) {
                const float w = wp[(size_t)k * MLP_OUT];
                a0 = fmaf(h0p[k],        w, a0);
                a1 = fmaf(h0p[1024 + k], w, a1);
                a2 = fmaf(h0p[2048 + k], w, a2);
                a3 = fmaf(h0p[3072 + k], w, a3);
            }
            p3[(size_t)(kc * 4 + 0) * MLP_OUT + c] = a0;
            p3[(size_t)(kc * 4 + 1) * MLP_OUT + c] = a1;
            p3[(size_t)(kc * 4 + 2) * MLP_OUT + c] = a2;
            p3[(size_t)(kc * 4 + 3) * MLP_OUT + c] = a3;
        }
        __syncthreads();
    }
    grid.sync();

    // ================= phase 4: combine 4 partials + b3 -> transposed/scaled mlpT, 392 tasks
    for (int task = blockIdx.x; task < 392; task += nblk) {
        const int cch = task >> 2, b = task & 3;
        const int d = cch * 256 + tid;
        if (d < MLPT_STRIDE) {
            int src = -1;
            float scale = 1.f;
            if (d < 24832) {
                const int l = d / 12416, r = d % 12416;
                const int base = l * MID_DIM;
                if (r < 8192) {
                    const int half = r >> 12;
                    const int rr = r & 4095;
                    const int i = rr >> 6, o = rr & 63;
                    src = base + o * 128 + i * 2 + half;
                    scale = INV2PI;
                } else if (r < 12288) {
                    const int rr = r - 8192;
                    const int i = rr >> 6, o = rr & 63;
                    src = base + 8192 + o * 65 + 1 + i;
                } else if (r < 12352) {
                    src = base + 8192 + (r - 12288) * 65;
                }
            } else {
                const int rr = d - 24832;
                const int base = 2 * MID_DIM;
                if (rr < 64)        { src = base + rr * 2;            scale = INV2PI; }
                else if (rr < 128)  { src = base + (rr - 64) * 2 + 1; scale = INV2PI; }
                else if (rr < 192)  { src = base + 128 + 1 + (rr - 128); }
                else if (rr == 192) { src = base + 128; }
            }
            float v = 0.f;
            if (src >= 0) {
                v = b3[src];
                #pragma unroll
                for (int j = 0; j < 4; ++j) v += p3[(size_t)(j * 4 + b) * MLP_OUT + src];
                v *= scale;
            }
            mlpT[(size_t)b * MLPT_STRIDE + d] = v;
        }
    }
    grid.sync();

    // ================= phase 5: fused ripple l0 -> l1 -> out + bypass, 512 tasks ========
    for (int task = blockIdx.x; task < 512; task += nblk) {
        const int b = task >> 7;
        const int t0 = (task & 127) * 32;
        const int lane = tid & 63, wid = tid >> 6, tb = wid * 8;
        const float* mb = mlpT + (size_t)b * MLPT_STRIDE;

        {   // stage layer-0 weights + out weights (flat float4 copy)
            const float4* src = reinterpret_cast<const float4*>(mb);
            float4* dst = reinterpret_cast<float4*>(s_w);
            for (int e = tid; e < 3104; e += 256) dst[e] = src[e];
            if (tid < 64)
                reinterpret_cast<float4*>(s_wo)[tid] =
                    reinterpret_cast<const float4*>(mb + 24832)[tid];
        }
        const float lw = lcw[lane], lb = lcb[lane];
        for (int e = tid; e < 2048; e += 256) {
            const int i = e >> 5, tt = e & 31;
            s_x[i * 36 + tt] = fmaf((float)(t0 + tt), lcw[i], lcb[i]);
        }
        __syncthreads();

        float acc[8];
        for (int layer = 0; layer < 2; ++layer) {
            const float bc = s_w[12288 + lane];
            #pragma unroll
            for (int j = 0; j < 8; ++j) acc[j] = bc;
            for (int i = 0; i < 64; ++i) {
                const float wsv = s_w[i * 64 + lane];
                const float wov = s_w[4096 + i * 64 + lane];
                const float bsv = s_w[8192 + i * 64 + lane];
                const float4 xa = *reinterpret_cast<const float4*>(&s_x[i * 36 + tb]);
                const float4 xb = *reinterpret_cast<const float4*>(&s_x[i * 36 + tb + 4]);
                const float xv[8] = {xa.x, xa.y, xa.z, xa.w, xb.x, xb.y, xb.z, xb.w};
                #pragma unroll
                for (int j = 0; j < 8; ++j) {
                    const float r = fmaf(wsv, xv[j], wov);
                    acc[j] = fmaf(hw_sin_rev(r), bsv, acc[j]);
                }
            }
            __syncthreads();
            if (layer == 0) {
                #pragma unroll
                for (int j = 0; j < 8; ++j)
                    s_x[lane * 36 + tb + j] = gelu_exact(acc[j]);
                const float4* src = reinterpret_cast<const float4*>(mb + 12416);
                float4* dst = reinterpret_cast<float4*>(s_w);
                for (int e = tid; e < 3104; e += 256) dst[e] = src[e];
                __syncthreads();
            }
        }

        {   // out-layer ripple + bypass, 64-lane butterfly per t
            const float wsO = s_wo[lane], woO = s_wo[64 + lane], bsO = s_wo[128 + lane];
            const float bcO = s_wo[192];
            const float bw0 = bypw[0] * INV2PI, bw1 = bypw[1] * INV2PI;
            const float bb0 = bypb[0], bb1 = bypb[1];
            #pragma unroll
            for (int j = 0; j < 8; ++j) {
                const int t = t0 + tb + j;
                const float v = gelu_exact(acc[j]);
                float s = hw_sin_rev(fmaf(wsO, v, woO)) * bsO;
                const float xb = fmaf((float)t, lw, lb);
                s = fmaf(hw_sin_rev(fmaf(bw0, xb, bw1)), bb1, s);
                #pragma unroll
                for (int m = 1; m < 64; m <<= 1) s += __shfl_xor(s, m, 64);
                if (lane == 0) s_red[tb + j] = s + bcO + bb0;
            }
        }
        __syncthreads();
        if (tid < 32) out[(size_t)b * SEQ + t0 + tid] = s_red[tid];
        __syncthreads();
    }
}

extern "C" void kernel_launch(void* const* d_in, const int* in_sizes, int n_in,
                              void* d_out, int out_size, void* d_ws, size_t ws_size,
                              hipStream_t stream) {
    const float* x    = (const float*)d_in[0];
    const float* w0   = (const float*)d_in[1];
    const float* b0   = (const float*)d_in[2];
    const float* w1   = (const float*)d_in[3];
    const float* b1   = (const float*)d_in[4];
    const float* g1   = (const float*)d_in[5];
    const float* bl1  = (const float*)d_in[6];
    const float* w2   = (const float*)d_in[7];
    const float* b2   = (const float*)d_in[8];
    const float* g2   = (const float*)d_in[9];
    const float* bl2  = (const float*)d_in[10];
    const float* w3   = (const float*)d_in[11];
    const float* b3   = (const float*)d_in[12];
    const float* lcw  = (const float*)d_in[13];
    const float* lcb  = (const float*)d_in[14];
    const float* bypw = (const float*)d_in[15];
    const float* bypb = (const float*)d_in[16];
    float* out = (float*)d_out;
    float* ws  = (float*)d_ws;

    int dev = 0;
    hipGetDevice(&dev);
    hipDeviceProp_t prop;
    hipGetDeviceProperties(&prop, dev);
    int occ = 0;
    hipOccupancyMaxActiveBlocksPerMultiprocessor(&occ, k_mega, 256, 0);
    int grid = occ * prop.multiProcessorCount;
    if (grid > 512) grid = 512;
    if (grid < 1)  grid = 1;

    void* args[] = {
        (void*)&x,  (void*)&w0, (void*)&b0,
        (void*)&w1, (void*)&b1, (void*)&g1, (void*)&bl1,
        (void*)&w2, (void*)&b2, (void*)&g2, (void*)&bl2,
        (void*)&w3, (void*)&b3, (void*)&lcw, (void*)&lcb,
        (void*)&bypw, (void*)&bypb, (void*)&out, (void*)&ws
    };
    hipLaunchCooperativeKernel((const void*)k_mega, dim3(grid), dim3(256),
                               args, 0, stream);
}

// Round 4
// 282.383 us; speedup vs baseline: 2.0387x; 2.0387x over previous
//
#include <hip/hip_runtime.h>
#include <math.h>

#define B_      4
#define IN_DIM  512
#define HID     1024
#define SEQ     4096
#define MID_DIM 12352          // 2*64*64 + 65*64
#define MLP_OUT 24897          // RL*MID_DIM + OUT_DIM
#define INV2PI  0.15915494309189535f

// transposed/pre-scaled weight layout, per b (stride MLPT_STRIDE):
//  layer l in {0,1} at l*12416: wsc[i][o] | wof[i][o] | bsv[i][o] | bc[o] | pad64
//  out layer at 24832: wsO/2pi (64) | woO/2pi (64) | bsO (64) | bcO | pad to 256
#define MLPT_STRIDE 25088

// ---- workspace layout (float offsets) ----
#define OFF_P0    0            // 8*4*1024 = 32768
#define OFF_P1    32768        // 4*4*1024 = 16384
#define OFF_P2    49152        // 4*4*1024 = 16384
#define OFF_H2    65536        // 4096
#define OFF_MLPT  69632        // 4*25088  = 100352

__device__ __forceinline__ float gelu_exact(float v) {
    return 0.5f * v * (1.0f + erff(v * 0.70710678118654752f));
}

__device__ __forceinline__ float hw_sin_rev(float r) {
    r = r - __builtin_rintf(r);
    return __builtin_amdgcn_sinf(r);
}

// ---------- x(4x512) @ w0 -> p0 (8 K-partials): grid (16,8), block 256 ----------
__global__ void k_gemm0(const float* __restrict__ x, const float* __restrict__ w0,
                        float* __restrict__ p0) {
    const int cch = blockIdx.x, kc = blockIdx.y;
    const int tid = threadIdx.x;
    __shared__ float xs[256];                 // [b][k64]
    {
        const int b = tid >> 6, k = tid & 63;
        xs[tid] = x[b * IN_DIM + kc * 64 + k];
    }
    __syncthreads();
    const int b = tid >> 6, cl = tid & 63;
    const int c = cch * 64 + cl;
    const float* wp = w0 + (size_t)(kc * 64) * HID + c;
    const float* xp = xs + b * 64;
    float acc = 0.f;
    #pragma unroll 16
    for (int k = 0; k < 64; ++k) acc = fmaf(xp[k], wp[(size_t)k * HID], acc);
    p0[(kc * 4 + b) * HID + c] = acc;
}

// ---------- h0=gelu(sum8 p0 + b0); h0 @ w1 -> p1 (4 K-partials): grid (16,4) ----------
__global__ void k_gemm1(const float* __restrict__ p0, const float* __restrict__ b0,
                        const float* __restrict__ w1, float* __restrict__ p1) {
    const int cch = blockIdx.x, kc = blockIdx.y;   // kc: 256-wide k slice
    const int tid = threadIdx.x;
    __shared__ float s_h[1024];               // [b][k256]
    for (int e = tid; e < 1024; e += 256) {
        const int b = e >> 8, kk = e & 255;
        const int kg = kc * 256 + kk;
        float v = b0[kg];
        #pragma unroll
        for (int j = 0; j < 8; ++j) v += p0[(j * 4 + b) * HID + kg];
        s_h[e] = gelu_exact(v);
    }
    __syncthreads();
    const int b = tid >> 6, cl = tid & 63;
    const int c = cch * 64 + cl;
    const float* wp = w1 + (size_t)(kc * 256) * HID + c;
    const float* hp = s_h + b * 256;
    float acc = 0.f;
    #pragma unroll 16
    for (int k = 0; k < 256; ++k) acc = fmaf(hp[k], wp[(size_t)k * HID], acc);
    p1[(kc * 4 + b) * HID + c] = acc;
}

// ---------- h1=gelu(LN(sum4 p1 + b1)) per block; h1 @ w2 -> p2 (4 K-partials): grid (16,4) ----------
__global__ void k_gemm2(const float* __restrict__ p1, const float* __restrict__ b1,
                        const float* __restrict__ g1, const float* __restrict__ bl1,
                        const float* __restrict__ w2, float* __restrict__ p2) {
    const int cch = blockIdx.x, kc = blockIdx.y;
    const int tid = threadIdx.x;
    __shared__ __align__(16) float vbuf[4096];   // [b][c]
    __shared__ float s_h[1024];                  // [b][k256]
    __shared__ float s_red[8];
    for (int e = tid; e < 4096; e += 256) {
        const int b = e >> 10, c = e & 1023;
        float v = b1[c];
        #pragma unroll
        for (int j = 0; j < 4; ++j) v += p1[(j * 4 + b) * HID + c];
        vbuf[e] = v;
    }
    __syncthreads();
    {
        const int b = tid >> 6, lane = tid & 63;
        float s1 = 0.f, s2 = 0.f;
        #pragma unroll
        for (int jj = 0; jj < 16; ++jj) {
            const float v = vbuf[b * 1024 + lane + 64 * jj];
            s1 += v; s2 += v * v;
        }
        #pragma unroll
        for (int m = 1; m < 64; m <<= 1) {
            s1 += __shfl_xor(s1, m, 64);
            s2 += __shfl_xor(s2, m, 64);
        }
        if (lane == 0) {
            const float mu = s1 * (1.0f / HID);
            s_red[b] = mu;
            s_red[4 + b] = rsqrtf(s2 * (1.0f / HID) - mu * mu + 1e-5f);
        }
    }
    __syncthreads();
    for (int e = tid; e < 1024; e += 256) {
        const int b = e >> 8, kk = e & 255;
        const int c = kc * 256 + kk;
        const float v = vbuf[b * 1024 + c];
        s_h[e] = gelu_exact((v - s_red[b]) * s_red[4 + b] * g1[c] + bl1[c]);
    }
    __syncthreads();
    const int b = tid >> 6, cl = tid & 63;
    const int c = cch * 64 + cl;
    const float* wp = w2 + (size_t)(kc * 256) * HID + c;
    const float* hp = s_h + b * 256;
    float acc = 0.f;
    #pragma unroll 16
    for (int k = 0; k < 256; ++k) acc = fmaf(hp[k], wp[(size_t)k * HID], acc);
    p2[(kc * 4 + b) * HID + c] = acc;
}

// ---------- h2 = gelu(LN(sum4 p2 + b2)): grid 4, block 1024 ----------
__global__ void k_lng2(const float* __restrict__ p2, const float* __restrict__ b2,
                       const float* __restrict__ g2, const float* __restrict__ bl2,
                       float* __restrict__ h2) {
    const int b = blockIdx.x, tid = threadIdx.x;
    float v = b2[tid];
    #pragma unroll
    for (int j = 0; j < 4; ++j) v += p2[(j * 4 + b) * HID + tid];
    float s1 = v, s2 = v * v;
    #pragma unroll
    for (int m = 1; m < 64; m <<= 1) {
        s1 += __shfl_xor(s1, m, 64);
        s2 += __shfl_xor(s2, m, 64);
    }
    __shared__ float r1[16], r2[16], s_mu, s_rs;
    const int lane = tid & 63, wid = tid >> 6;
    if (lane == 0) { r1[wid] = s1; r2[wid] = s2; }
    __syncthreads();
    if (tid == 0) {
        float a = 0.f, c = 0.f;
        #pragma unroll
        for (int j = 0; j < 16; ++j) { a += r1[j]; c += r2[j]; }
        const float mu = a * (1.0f / HID);
        s_mu = mu;
        s_rs = rsqrtf(c * (1.0f / HID) - mu * mu + 1e-5f);
    }
    __syncthreads();
    h2[b * HID + tid] = gelu_exact((v - s_mu) * s_rs * g2[tid] + bl2[tid]);
}

// ---------- h2(4x1024) @ w3 -> mlpT (transposed/scaled, direct): grid 390, block 256 ----------
// lane cl = column within 64-chunk; wave = b. h2 read via scalar (wave-uniform) loads.
__global__ void k_gemm3T(const float* __restrict__ h2, const float* __restrict__ w3,
                         const float* __restrict__ b3, float* __restrict__ mlpT) {
    const int tid = threadIdx.x;
    const int cl = tid & 63;
    const int bu = __builtin_amdgcn_readfirstlane(tid >> 6);
    const int c_raw = blockIdx.x * 64 + cl;
    const bool valid = c_raw < MLP_OUT;
    const int c = valid ? c_raw : (MLP_OUT - 1);
    const float* hp = h2 + bu * HID;
    const float* wp = w3 + c;
    float acc = 0.f;
    #pragma unroll 16
    for (int k = 0; k < 1024; ++k)
        acc = fmaf(hp[k], wp[(size_t)k * MLP_OUT], acc);
    if (!valid) return;
    const float v = acc + b3[c];
    // inverse permutation c -> d in mlpT, with 1/2pi pre-scale on frequency/phase
    int d; float sc = 1.f;
    if (c < 2 * MID_DIM) {
        const int l = c / MID_DIM;
        const int rel = c - l * MID_DIM;
        if (rel < 8192) {
            const int o = rel >> 7, low = rel & 127;
            d = l * 12416 + (low & 1) * 4096 + (low >> 1) * 64 + o;
            sc = INV2PI;
        } else {
            const int r2 = rel - 8192;
            const int o = r2 / 65, j = r2 % 65;
            d = (j == 0) ? (l * 12416 + 12288 + o)
                         : (l * 12416 + 8192 + (j - 1) * 64 + o);
        }
    } else {
        const int rel = c - 2 * MID_DIM;
        if (rel < 128)       { d = 24832 + (rel & 1) * 64 + (rel >> 1); sc = INV2PI; }
        else if (rel == 128) { d = 24832 + 192; }
        else                 { d = 24832 + 128 + (rel - 129); }
    }
    mlpT[(size_t)bu * MLPT_STRIDE + d] = v * sc;
}

// ---------- fused ripple: layer0 -> layer1 -> out-layer + bypass ----------
// grid (SEQ/32, B), block 256 (4 waves x 8 t). lane = o.
__global__ void __launch_bounds__(256, 2) k_ripple(
        const float* __restrict__ mlpT, const float* __restrict__ lcw,
        const float* __restrict__ lcb, const float* __restrict__ bypw,
        const float* __restrict__ bypb, float* __restrict__ out) {
    const int tid = threadIdx.x;
    const int b = blockIdx.y;
    const int t0 = blockIdx.x * 32;
    const int lane = tid & 63, wid = tid >> 6, tb = wid * 8;

    __shared__ __align__(16) float s_w[12416];
    __shared__ __align__(16) float s_x[2304];    // x[i][t], stride 36
    __shared__ __align__(16) float s_wo[256];
    __shared__ float s_red[32];

    const float* mb = mlpT + (size_t)b * MLPT_STRIDE;

    {
        const float4* src = reinterpret_cast<const float4*>(mb);
        float4* dst = reinterpret_cast<float4*>(s_w);
        for (int e = tid; e < 3104; e += 256) dst[e] = src[e];
        if (tid < 64)
            reinterpret_cast<float4*>(s_wo)[tid] =
                reinterpret_cast<const float4*>(mb + 24832)[tid];
    }
    const float lw = lcw[lane], lb = lcb[lane];
    for (int e = tid; e < 2048; e += 256) {
        const int i = e >> 5, tt = e & 31;
        s_x[i * 36 + tt] = fmaf((float)(t0 + tt), lcw[i], lcb[i]);
    }
    __syncthreads();

    float acc[8];
    for (int layer = 0; layer < 2; ++layer) {
        const float bc = s_w[12288 + lane];
        #pragma unroll
        for (int j = 0; j < 8; ++j) acc[j] = bc;
        for (int i = 0; i < 64; ++i) {
            const float wsv = s_w[i * 64 + lane];
            const float wov = s_w[4096 + i * 64 + lane];
            const float bsv = s_w[8192 + i * 64 + lane];
            const float4 xa = *reinterpret_cast<const float4*>(&s_x[i * 36 + tb]);
            const float4 xb = *reinterpret_cast<const float4*>(&s_x[i * 36 + tb + 4]);
            const float xv[8] = {xa.x, xa.y, xa.z, xa.w, xb.x, xb.y, xb.z, xb.w};
            #pragma unroll
            for (int j = 0; j < 8; ++j) {
                const float r = fmaf(wsv, xv[j], wov);
                acc[j] = fmaf(hw_sin_rev(r), bsv, acc[j]);
            }
        }
        __syncthreads();
        if (layer == 0) {
            #pragma unroll
            for (int j = 0; j < 8; ++j)
                s_x[lane * 36 + tb + j] = gelu_exact(acc[j]);
            const float4* src = reinterpret_cast<const float4*>(mb + 12416);
            float4* dst = reinterpret_cast<float4*>(s_w);
            for (int e = tid; e < 3104; e += 256) dst[e] = src[e];
            __syncthreads();
        }
    }

    {
        const float wsO = s_wo[lane], woO = s_wo[64 + lane], bsO = s_wo[128 + lane];
        const float bcO = s_wo[192];
        const float bw0 = bypw[0] * INV2PI, bw1 = bypw[1] * INV2PI;
        const float bb0 = bypb[0], bb1 = bypb[1];
        #pragma unroll
        for (int j = 0; j < 8; ++j) {
            const int t = t0 + tb + j;
            const float v = gelu_exact(acc[j]);
            float s = hw_sin_rev(fmaf(wsO, v, woO)) * bsO;
            const float xb = fmaf((float)t, lw, lb);
            s = fmaf(hw_sin_rev(fmaf(bw0, xb, bw1)), bb1, s);
            #pragma unroll
            for (int m = 1; m < 64; m <<= 1) s += __shfl_xor(s, m, 64);
            if (lane == 0) s_red[tb + j] = s + bcO + bb0;
        }
    }
    __syncthreads();
    if (tid < 32) out[(size_t)b * SEQ + t0 + tid] = s_red[tid];
}

extern "C" void kernel_launch(void* const* d_in, const int* in_sizes, int n_in,
                              void* d_out, int out_size, void* d_ws, size_t ws_size,
                              hipStream_t stream) {
    const float* x    = (const float*)d_in[0];
    const float* w0   = (const float*)d_in[1];
    const float* b0   = (const float*)d_in[2];
    const float* w1   = (const float*)d_in[3];
    const float* b1   = (const float*)d_in[4];
    const float* g1   = (const float*)d_in[5];
    const float* bl1  = (const float*)d_in[6];
    const float* w2   = (const float*)d_in[7];
    const float* b2   = (const float*)d_in[8];
    const float* g2   = (const float*)d_in[9];
    const float* bl2  = (const float*)d_in[10];
    const float* w3   = (const float*)d_in[11];
    const float* b3   = (const float*)d_in[12];
    const float* lcw  = (const float*)d_in[13];
    const float* lcb  = (const float*)d_in[14];
    const float* bypw = (const float*)d_in[15];
    const float* bypb = (const float*)d_in[16];
    float* out = (float*)d_out;
    float* ws  = (float*)d_ws;

    float* p0   = ws + OFF_P0;
    float* p1   = ws + OFF_P1;
    float* p2   = ws + OFF_P2;
    float* h2   = ws + OFF_H2;
    float* mlpT = ws + OFF_MLPT;

    k_gemm0 <<<dim3(16, 8), 256, 0, stream>>>(x, w0, p0);
    k_gemm1 <<<dim3(16, 4), 256, 0, stream>>>(p0, b0, w1, p1);
    k_gemm2 <<<dim3(16, 4), 256, 0, stream>>>(p1, b1, g1, bl1, w2, p2);
    k_lng2  <<<B_, 1024,    0, stream>>>(p2, b2, g2, bl2, h2);
    k_gemm3T<<<390, 256,    0, stream>>>(h2, w3, b3, mlpT);
    k_ripple<<<dim3(SEQ / 32, B_), 256, 0, stream>>>(mlpT, lcw, lcb, bypw, bypb, out);
}